// Round 15
// baseline (1539.063 us; speedup 1.0000x reference)
//
#include <hip/hip_runtime.h>
#include <hip/hip_cooperative_groups.h>
#include <math.h>

namespace cg = cooperative_groups;

// ---------------------------------------------------------------------------
// ChebNet: 3x ChebConv(S=7) + ReLU, then FC(64->1).
// N=50000 nodes, E=800000 edges, F_IN=16, H=64.
// R15: cooperative per-layer SpMV chain, now with (a) occupancy-queried grid
// size, (b) per-launch error check falling back to the verified R12 per-step
// spmv_slice path. Slices 2x[N][32] fp16 (3.2MB + 0.6MB cw < 4MB per-XCD L2,
// parity-pinned) to keep gathers L2-warm across the 6 Cheb steps.
// Keeps: padded CSR (B=8, no predication), XCD-cohort scatter, MFMA GEMM on
// pre-packed W frags, fused FC head, single prep kernel.
// ---------------------------------------------------------------------------

#define WS_ALIGN(x) (((size_t)(x) + 255) & ~(size_t)255)

using f16x8 = __attribute__((ext_vector_type(8))) _Float16;
using f32x4 = __attribute__((ext_vector_type(4))) float;

__device__ inline float h2f_bits(unsigned int b) {
  unsigned short s = (unsigned short)(b & 0xffffu);
  _Float16 h;
  __builtin_memcpy(&h, &s, 2);
  return (float)h;
}
__device__ inline unsigned short f2h_bits(float f) {
  _Float16 h = (_Float16)f;
  unsigned short s;
  __builtin_memcpy(&s, &h, 2);
  return s;
}
union H8 {
  uint4 q;
  _Float16 h[8];
  ushort us[8];
};

__global__ __launch_bounds__(256) void hist_kernel(const int* __restrict__ row, int E,
                                                   int* __restrict__ deg) {
  int i = blockIdx.x * 256 + threadIdx.x;
  if (i < E) atomicAdd(&deg[row[i]], 1);
}

// ---- hierarchical scan over PADDED degrees (pad = ceil(deg/8)*8) ----
__global__ __launch_bounds__(256) void scan_sum_kernel(const int* __restrict__ deg,
                                                       int* __restrict__ bsum, int n) {
  int base = blockIdx.x * 1024 + threadIdx.x;
  int v = 0;
#pragma unroll
  for (int u = 0; u < 4; ++u) {
    int i = base + u * 256;
    if (i < n) v += (deg[i] + 7) & ~7;
  }
#pragma unroll
  for (int off = 32; off > 0; off >>= 1) v += __shfl_down(v, off, 64);
  __shared__ int ws[4];
  int lane = threadIdx.x & 63, wave = threadIdx.x >> 6;
  if (lane == 0) ws[wave] = v;
  __syncthreads();
  if (threadIdx.x == 0) bsum[blockIdx.x] = ws[0] + ws[1] + ws[2] + ws[3];
}

__global__ __launch_bounds__(64) void scan_bsum_kernel(int* __restrict__ bsum, int nb) {
  int t = threadIdx.x;
  int v = (t < nb) ? bsum[t] : 0;
  int sc = v;
#pragma unroll
  for (int off = 1; off < 64; off <<= 1) {
    int tv = __shfl_up(sc, off, 64);
    if (t >= off) sc += tv;
  }
  if (t < nb) bsum[t] = sc - v;
}

__global__ __launch_bounds__(256) void scan_out_kernel(const int* __restrict__ deg,
                                                       const int* __restrict__ bsum,
                                                       int* __restrict__ row_ptr,
                                                       int* __restrict__ cursor,
                                                       float* __restrict__ dis, int n) {
  int base = blockIdx.x * 1024 + threadIdx.x * 4;
  int loc[4];
  int s = 0;
#pragma unroll
  for (int u = 0; u < 4; ++u) {
    int i = base + u;
    loc[u] = (i < n) ? deg[i] : 0;
    s += (loc[u] + 7) & ~7;
  }
  int lane = threadIdx.x & 63, wave = threadIdx.x >> 6;
  int sc = s;
#pragma unroll
  for (int off = 1; off < 64; off <<= 1) {
    int tv = __shfl_up(sc, off, 64);
    if (lane >= off) sc += tv;
  }
  __shared__ int wtot[4];
  if (lane == 63) wtot[wave] = sc;
  __syncthreads();
  int pre = sc - s + bsum[blockIdx.x];
  for (int w = 0; w < wave; ++w) pre += wtot[w];
  if (blockIdx.x == 0 && threadIdx.x == 0) row_ptr[0] = 0;
  int running = pre;
#pragma unroll
  for (int u = 0; u < 4; ++u) {
    int i = base + u;
    if (i < n) {
      cursor[i] = running;
      dis[i] = (loc[u] > 0) ? (1.0f / sqrtf((float)loc[u])) : 0.0f;
      running += (loc[u] + 7) & ~7;
      row_ptr[i + 1] = running;
    }
  }
}

// XCD-cohort scatter: cohort c = blockIdx&7 owns rows [c*n/8,(c+1)*n/8).
__global__ __launch_bounds__(256) void scatter_x8(const int* __restrict__ row,
                                                  const int* __restrict__ col, int E,
                                                  int* __restrict__ cursor,
                                                  const float* __restrict__ dis,
                                                  const float* __restrict__ lamp,
                                                  unsigned int* __restrict__ cw, int n) {
  int c = blockIdx.x & 7;
  int j = blockIdx.x >> 3;
  int nj = gridDim.x >> 3;
  int lo = (c * n) >> 3;
  int hi = ((c + 1) * n) >> 3;
  float sc = -(2.0f / lamp[0]);
  for (int i = j * 256 + threadIdx.x; i < E; i += nj * 256) {
    int r = row[i];
    if (r < lo || r >= hi) continue;
    int cc = col[i];
    int pos = atomicAdd(&cursor[r], 1);
    float w = sc * dis[r] * dis[cc];
    cw[pos] = ((unsigned int)cc << 16) | (unsigned int)f2h_bits(w);
  }
}

// Pack W ([KREAL][64] f32, zero-padded to KT*32) into MFMA B-fragment order.
__device__ inline void wpk_pack(const float* __restrict__ W, ushort* __restrict__ Wpk,
                                int KREAL, int t) {
  int kt = t >> 8, nt = (t >> 6) & 3, l = t & 63;
  int col = nt * 16 + (l & 15);
  int kb = kt * 32 + ((l >> 4) << 3);
  ushort tmp[8];
#pragma unroll
  for (int j = 0; j < 8; ++j) {
    int k = kb + j;
    float v = (k < KREAL) ? W[(size_t)k * 64 + col] : 0.0f;
    tmp[j] = f2h_bits(v);
  }
  ushort4* dst = (ushort4*)Wpk + (size_t)((kt * 4 + nt) * 64 + l) * 2;
  dst[0] = make_ushort4(tmp[0], tmp[1], tmp[2], tmp[3]);
  dst[1] = make_ushort4(tmp[4], tmp[5], tmp[6], tmp[7]);
}

// One prep kernel: blocks [0,4) Wpk1, [4,18) Wpk2, [18,32) Wpk3, [32,..) x->T1.
__global__ __launch_bounds__(256) void prep_all_kernel(
    const float* __restrict__ W1, const float* __restrict__ W2,
    const float* __restrict__ W3, ushort* __restrict__ Wpk1, ushort* __restrict__ Wpk2,
    ushort* __restrict__ Wpk3, const float* __restrict__ x, ushort* __restrict__ T1,
    int n) {
  int b = blockIdx.x;
  if (b < 4) {
    wpk_pack(W1, Wpk1, 112, b * 256 + threadIdx.x);
  } else if (b < 18) {
    wpk_pack(W2, Wpk2, 448, (b - 4) * 256 + threadIdx.x);
  } else if (b < 32) {
    wpk_pack(W3, Wpk3, 448, (b - 18) * 256 + threadIdx.x);
  } else {
    int t = (b - 32) * 256 + threadIdx.x;
    if (t < n * 4) {
      int row = t >> 2, q = t & 3;
      float4 v = ((const float4*)x)[(size_t)row * 4 + q];
      ushort4 o;
      o.x = f2h_bits(v.x);
      o.y = f2h_bits(v.y);
      o.z = f2h_bits(v.z);
      o.w = f2h_bits(v.w);
      ((ushort4*)T1)[(size_t)row * 4 + q] = o;
    } else if (t < n * 8) {
      int t2 = t - n * 4;
      ((ushort4*)(T1 + (size_t)7 * n * 16))[t2] = make_ushort4(0, 0, 0, 0);
    }
  }
}

// ---- shared spmv step body (padded CSR, B=8, 16B/lane) ----
template <int SW>
__device__ inline void spmv_row(const int* __restrict__ row_ptr,
                                const unsigned int* __restrict__ cw, float diag,
                                const ushort* __restrict__ xin,
                                const ushort* __restrict__ sub, ushort* __restrict__ xout,
                                int i, int f8, int grpbase, bool cheb) {
  constexpr int LPR = SW / 8;
  constexpr int B = 8;
  constexpr int EPL = B / LPR;
  H8 xd;
  xd.q = *(const uint4*)(xin + (size_t)i * SW + f8 * 8);
  float a[8];
#pragma unroll
  for (int j = 0; j < 8; ++j) a[j] = diag * (float)xd.h[j];
  int s = row_ptr[i], e = row_ptr[i + 1];
  for (int j0 = s; j0 < e; j0 += B) {
    unsigned int pv[EPL];
#pragma unroll
    for (int u = 0; u < EPL; ++u) pv[u] = cw[j0 + f8 * EPL + u];
    H8 xv[B];
    float ww[B];
#pragma unroll
    for (int u = 0; u < B; ++u) {
      unsigned int pu = (unsigned int)__shfl((int)pv[u % EPL], grpbase + u / EPL, 64);
      ww[u] = h2f_bits(pu);
      xv[u].q = *(const uint4*)(xin + (size_t)(pu >> 16) * SW + f8 * 8);
    }
#pragma unroll
    for (int u = 0; u < B; ++u)
#pragma unroll
      for (int j = 0; j < 8; ++j) a[j] += ww[u] * (float)xv[u].h[j];
  }
  float r[8];
  if (cheb) {
    H8 sv;
    sv.q = *(const uint4*)(sub + (size_t)i * SW + f8 * 8);
#pragma unroll
    for (int j = 0; j < 8; ++j) r[j] = 2.0f * a[j] - (float)sv.h[j];
  } else {
#pragma unroll
    for (int j = 0; j < 8; ++j) r[j] = a[j];
  }
  H8 o;
#pragma unroll
  for (int j = 0; j < 8; ++j) o.us[j] = f2h_bits(r[j]);
  *(uint4*)(xout + (size_t)i * SW + f8 * 8) = o.q;
}

// ---------------------------------------------------------------------------
// Cooperative per-layer Cheb chain: 6 spmv steps with grid.sync between.
// Slot (k,s) at base + (SLICES*k+s)*ssz; slice = blockIdx parity (pinned).
// ---------------------------------------------------------------------------
template <int SW, int SLICES>
__global__ __launch_bounds__(256) void coop_cheb(const int* __restrict__ row_ptr,
                                                 const unsigned int* __restrict__ cw,
                                                 const float* __restrict__ lamp,
                                                 ushort* __restrict__ base, int ssz,
                                                 int n) {
  constexpr int LPR = SW / 8;
  constexpr int RPB = 256 / LPR;
  cg::grid_group grid = cg::this_grid();
  int sl = (SLICES == 2) ? (blockIdx.x & 1) : 0;
  int bx = (SLICES == 2) ? (blockIdx.x >> 1) : blockIdx.x;
  int nbx = (SLICES == 2) ? (gridDim.x >> 1) : gridDim.x;
  int f8 = threadIdx.x;
  int ty = threadIdx.y;
  int lane = (ty * LPR + f8) & 63;
  int grpbase = lane - f8;
  float diag = 2.0f / lamp[0] - 1.0f;

  for (int k = 1; k < 7; ++k) {
    const ushort* xin = base + (size_t)(SLICES * (k - 1) + sl) * ssz;
    const ushort* sub =
        (k >= 2) ? (base + (size_t)(SLICES * (k - 2) + sl) * ssz) : (const ushort*)nullptr;
    ushort* xout = base + (size_t)(SLICES * k + sl) * ssz;
    for (int i = bx * RPB + ty; i < n; i += nbx * RPB)
      spmv_row<SW>(row_ptr, cw, diag, xin, sub, xout, i, f8, grpbase, k >= 2);
    grid.sync();
  }
}

// ---- fallback: one spmv step per launch (R12-verified path) ----
template <int SW, int MODE, int SLICES>
__global__ __launch_bounds__(256) void spmv_slice(const int* __restrict__ row_ptr,
                                                  const unsigned int* __restrict__ cw,
                                                  const float* __restrict__ lamp,
                                                  const ushort* __restrict__ xin,
                                                  const ushort* __restrict__ sub,
                                                  ushort* __restrict__ xout, int ssz,
                                                  int n) {
  constexpr int LPR = SW / 8;
  constexpr int RPB = 256 / LPR;
  int bx = blockIdx.x;
  if (SLICES == 2) {
    int sl = bx & 1;
    bx >>= 1;
    xin += (size_t)sl * ssz;
    if (MODE == 1) sub += (size_t)sl * ssz;
    xout += (size_t)sl * ssz;
  }
  int i = bx * RPB + threadIdx.y;
  if (i >= n) return;
  int f8 = threadIdx.x;
  int lane = (threadIdx.y * LPR + f8) & 63;
  int grpbase = lane - f8;
  float diag = 2.0f / lamp[0] - 1.0f;
  spmv_row<SW>(row_ptr, cw, diag, xin, sub, xout, i, f8, grpbase, MODE == 1);
}

// ---------------------------------------------------------------------------
// MFMA GEMM over slot-major slices.
// SW=32: slot=kt, off=(l>>4)*8.  SW=16: slot=2kt+((l>>4)>>1), off=((l>>4)&1)*8.
// Non-LAST: bias+relu -> fp16 slices (slot 0/1 of dst).
// LAST: fused FC head (in-register bias+relu+dot, 16-lane shfl_xor reduce).
// ---------------------------------------------------------------------------
template <int SW, int KT, bool LAST>
__global__ __launch_bounds__(256) void gemm_mfma(const ushort* __restrict__ A,
                                                 const ushort* __restrict__ Wpk,
                                                 const float* __restrict__ bias,
                                                 ushort* __restrict__ dsth,
                                                 const float* __restrict__ wfc,
                                                 const float* __restrict__ bfc,
                                                 float* __restrict__ dout, int n) {
  int l = threadIdx.x & 63;
  int tile = blockIdx.x * 4 + (threadIdx.x >> 6);
  int r0 = tile * 16;
  if (r0 >= n) return;
  size_t slotsz = (size_t)n * SW;
  int row = r0 + (l & 15);
  const f16x8* bp = (const f16x8*)Wpk + l;
  f32x4 c[4] = {{0.f, 0.f, 0.f, 0.f},
                {0.f, 0.f, 0.f, 0.f},
                {0.f, 0.f, 0.f, 0.f},
                {0.f, 0.f, 0.f, 0.f}};
#pragma unroll
  for (int kt = 0; kt < KT; ++kt) {
    int slot, off;
    if constexpr (SW == 32) {
      slot = kt;
      off = (l >> 4) << 3;
    } else {
      slot = 2 * kt + ((l >> 4) >> 1);
      off = ((l >> 4) & 1) << 3;
    }
    f16x8 af = *(const f16x8*)(A + slot * slotsz + (size_t)row * SW + off);
#pragma unroll
    for (int nt = 0; nt < 4; ++nt) {
      f16x8 bf = bp[(kt * 4 + nt) * 64];
      c[nt] = __builtin_amdgcn_mfma_f32_16x16x32_f16(af, bf, c[nt], 0, 0, 0);
    }
  }
  int rb = r0 + ((l >> 4) << 2);
  int cc = l & 15;
  if (LAST) {
    float bfc0 = bfc[0];
#pragma unroll
    for (int j = 0; j < 4; ++j) {
      float part = 0.0f;
#pragma unroll
      for (int nt = 0; nt < 4; ++nt) {
        int col = nt * 16 + cc;
        part += fmaxf(c[nt][j] + bias[col], 0.0f) * wfc[col];
      }
#pragma unroll
      for (int m = 1; m < 16; m <<= 1) part += __shfl_xor(part, m, 64);
      if (cc == 0) dout[rb + j] = part + bfc0;
    }
  } else {
    size_t dslot = (size_t)n * 32;
#pragma unroll
    for (int nt = 0; nt < 4; ++nt) {
      int col = nt * 16 + cc;
      float bv = bias[col];
      ushort* dbase = dsth + (col >> 5) * dslot + (col & 31);
#pragma unroll
      for (int j = 0; j < 4; ++j) {
        float v = fmaxf(c[nt][j] + bv, 0.0f);
        dbase[(size_t)(rb + j) * 32] = f2h_bits(v);
      }
    }
  }
}

extern "C" void kernel_launch(void* const* d_in, const int* in_sizes, int n_in, void* d_out,
                              int out_size, void* d_ws, size_t ws_size, hipStream_t stream) {
  const float* x = (const float*)d_in[0];
  const int* ei = (const int*)d_in[1];
  const float* lamp = (const float*)d_in[2];
  const float* W1 = (const float*)d_in[3];
  const float* b1 = (const float*)d_in[4];
  const float* W2 = (const float*)d_in[5];
  const float* b2 = (const float*)d_in[6];
  const float* W3 = (const float*)d_in[7];
  const float* b3 = (const float*)d_in[8];
  const float* Wfc = (const float*)d_in[9];
  const float* bfc = (const float*)d_in[10];

  const int N = in_sizes[0] / 16;  // 50000 (< 65536 required for packing)
  const int E = in_sizes[1] / 2;
  const int* row = ei;
  const int* col = ei + E;

  // ---- workspace carve ----
  char* p = (char*)d_ws;
  auto alloc = [&](size_t bytes) {
    char* r = p;
    p += WS_ALIGN(bytes);
    return r;
  };
  const size_t EPAD = (size_t)E + 8 * (size_t)N;
  int* deg = (int*)alloc((size_t)N * 4);
  int* row_ptr = (int*)alloc((size_t)(N + 1) * 4);
  int* cursor = (int*)alloc((size_t)N * 4);
  unsigned int* cw = (unsigned int*)alloc(EPAD * 4);
  float* dis = (float*)alloc((size_t)N * 4);
  int* bsum = (int*)alloc(256 * 4);
  ushort* T1 = (ushort*)alloc((size_t)8 * N * 16 * 2);    // 8 slots [N][16] (slot7 = pad)
  ushort* TXC = (ushort*)alloc((size_t)14 * N * 32 * 2);  // 14 slots [N][32], idx 2k+s
  ushort* Wpk1 = (ushort*)alloc((size_t)4 * 256 * 8 * 2);
  ushort* Wpk2 = (ushort*)alloc((size_t)14 * 256 * 8 * 2);
  ushort* Wpk3 = (ushort*)alloc((size_t)14 * 256 * 8 * 2);
  (void)ws_size;
  (void)n_in;
  (void)out_size;

  // ---- cooperative capability probe (host-side queries only) ----
  int dev = 0;
  (void)hipGetDevice(&dev);
  int coopAttr = 0;
  (void)hipDeviceGetAttribute(&coopAttr, hipDeviceAttributeCooperativeLaunch, dev);
  int numCU = 0;
  (void)hipDeviceGetAttribute(&numCU, hipDeviceAttributeMultiprocessorCount, dev);
  int nb16 = 0, nb32 = 0;
  (void)hipOccupancyMaxActiveBlocksPerMultiprocessor(&nb16, coop_cheb<16, 1>, 256, 0);
  (void)hipOccupancyMaxActiveBlocksPerMultiprocessor(&nb32, coop_cheb<32, 2>, 256, 0);
  int grid16 = numCU * nb16;
  if (grid16 > 1024) grid16 = 1024;
  grid16 &= ~7;
  int grid32 = numCU * nb32;
  if (grid32 > 1024) grid32 = 1024;
  grid32 &= ~15;
  bool coop16 = coopAttr && grid16 >= 64;
  bool coop32 = coopAttr && grid32 >= 64;

  // ---- CSR build (padded rows; cw pre-zeroed so pads are col=0,w=+0) ----
  (void)hipMemsetAsync(deg, 0, (size_t)N * 4, stream);
  (void)hipMemsetAsync(cw, 0, EPAD * 4, stream);
  hist_kernel<<<(E + 255) / 256, 256, 0, stream>>>(row, E, deg);
  int nb = (N + 1023) / 1024;
  scan_sum_kernel<<<nb, 256, 0, stream>>>(deg, bsum, N);
  scan_bsum_kernel<<<1, 64, 0, stream>>>(bsum, nb);
  scan_out_kernel<<<nb, 256, 0, stream>>>(deg, bsum, row_ptr, cursor, dis, N);
  scatter_x8<<<2048, 256, 0, stream>>>(row, col, E, cursor, dis, lamp, cw, N);

  // ---- fused prep: W packing + x conversion ----
  prep_all_kernel<<<32 + (N * 8 + 255) / 256, 256, 0, stream>>>(W1, W2, W3, Wpk1, Wpk2, Wpk3,
                                                                x, T1, N);

  int nI = N;

  // ---- layer 1: coop chain on [N][16] slots, fallback = per-step ----
  {
    int ssz = N * 16;
    bool done = false;
    if (coop16) {
      void* args[] = {&row_ptr, &cw, &lamp, &T1, &ssz, &nI};
      hipError_t ce = hipLaunchCooperativeKernel((void*)coop_cheb<16, 1>, dim3(grid16),
                                                 dim3(2, 128), args, 0, stream);
      done = (ce == hipSuccess);
    }
    if (!done) {
      auto S = [&](int k) { return T1 + (size_t)k * ssz; };
      dim3 bs(2, 128);
      int gs = (N + 127) / 128;
      spmv_slice<16, 0, 1><<<gs, bs, 0, stream>>>(row_ptr, cw, lamp, S(0), nullptr, S(1), ssz,
                                                  N);
      for (int k = 2; k < 7; ++k)
        spmv_slice<16, 1, 1><<<gs, bs, 0, stream>>>(row_ptr, cw, lamp, S(k - 1), S(k - 2),
                                                    S(k), ssz, N);
    }
    gemm_mfma<16, 4, false><<<(N / 16 + 3) / 4 + 1, 256, 0, stream>>>(T1, Wpk1, b1, TXC,
                                                                      nullptr, nullptr,
                                                                      nullptr, N);
  }

  // ---- layers 2,3: coop chains on 2x[N][32] slices, fallback = per-step ----
  for (int layer = 2; layer <= 3; ++layer) {
    int ssz = N * 32;
    bool done = false;
    if (coop32) {
      void* args[] = {&row_ptr, &cw, &lamp, &TXC, &ssz, &nI};
      hipError_t ce = hipLaunchCooperativeKernel((void*)coop_cheb<32, 2>, dim3(grid32),
                                                 dim3(4, 64), args, 0, stream);
      done = (ce == hipSuccess);
    }
    if (!done) {
      auto S = [&](int k) { return TXC + (size_t)(2 * k) * ssz; };
      dim3 bs(4, 64);
      int gs = 2 * ((N + 63) / 64);
      spmv_slice<32, 0, 2><<<gs, bs, 0, stream>>>(row_ptr, cw, lamp, S(0), nullptr, S(1), ssz,
                                                  N);
      for (int k = 2; k < 7; ++k)
        spmv_slice<32, 1, 2><<<gs, bs, 0, stream>>>(row_ptr, cw, lamp, S(k - 1), S(k - 2),
                                                    S(k), ssz, N);
    }
    if (layer == 2)
      gemm_mfma<32, 14, false><<<(N / 16 + 3) / 4 + 1, 256, 0, stream>>>(TXC, Wpk2, b2, TXC,
                                                                         nullptr, nullptr,
                                                                         nullptr, N);
    else
      gemm_mfma<32, 14, true><<<(N / 16 + 3) / 4 + 1, 256, 0, stream>>>(TXC, Wpk3, b3,
                                                                        nullptr, Wfc, bfc,
                                                                        (float*)d_out, N);
  }
}

// Round 16
// 388.565 us; speedup vs baseline: 3.9609x; 3.9609x over previous
//
#include <hip/hip_runtime.h>
#include <math.h>

// ---------------------------------------------------------------------------
// ChebNet: 3x ChebConv(S=7) + ReLU, then FC(64->1).
// N=50000 nodes, E=800000 edges, F_IN=16, H=64.
// R16 = R13 restored (best measured: 390 us). Coop-chain experiment (R14/15)
// removed: cg::grid_group::sync costs ~100s of us on 8-XCD MI355X (cross-XCD
// barrier atomics), dwarfing any L2-retention gain. Gather path is at the L3
// random-line service floor (~6 TB/s): R12-vs-R13 byte/request null A/B.
// Structure: padded CSR (B=8, no predication), XCD-cohort scatter, dense
// [N][64] fp16 T_k buffers, MFMA GEMM on pre-packed W frags, fused FC head,
// single prep kernel.
// ---------------------------------------------------------------------------

#define WS_ALIGN(x) (((size_t)(x) + 255) & ~(size_t)255)

using f16x8 = __attribute__((ext_vector_type(8))) _Float16;
using f32x4 = __attribute__((ext_vector_type(4))) float;

__device__ inline float h2f_bits(unsigned int b) {
  unsigned short s = (unsigned short)(b & 0xffffu);
  _Float16 h;
  __builtin_memcpy(&h, &s, 2);
  return (float)h;
}
__device__ inline unsigned short f2h_bits(float f) {
  _Float16 h = (_Float16)f;
  unsigned short s;
  __builtin_memcpy(&s, &h, 2);
  return s;
}
union H8 {
  uint4 q;
  _Float16 h[8];
  ushort us[8];
};

__global__ __launch_bounds__(256) void hist_kernel(const int* __restrict__ row, int E,
                                                   int* __restrict__ deg) {
  int i = blockIdx.x * 256 + threadIdx.x;
  if (i < E) atomicAdd(&deg[row[i]], 1);
}

// ---- hierarchical scan over PADDED degrees (pad = ceil(deg/8)*8) ----
__global__ __launch_bounds__(256) void scan_sum_kernel(const int* __restrict__ deg,
                                                       int* __restrict__ bsum, int n) {
  int base = blockIdx.x * 1024 + threadIdx.x;
  int v = 0;
#pragma unroll
  for (int u = 0; u < 4; ++u) {
    int i = base + u * 256;
    if (i < n) v += (deg[i] + 7) & ~7;
  }
#pragma unroll
  for (int off = 32; off > 0; off >>= 1) v += __shfl_down(v, off, 64);
  __shared__ int ws[4];
  int lane = threadIdx.x & 63, wave = threadIdx.x >> 6;
  if (lane == 0) ws[wave] = v;
  __syncthreads();
  if (threadIdx.x == 0) bsum[blockIdx.x] = ws[0] + ws[1] + ws[2] + ws[3];
}

__global__ __launch_bounds__(64) void scan_bsum_kernel(int* __restrict__ bsum, int nb) {
  int t = threadIdx.x;
  int v = (t < nb) ? bsum[t] : 0;
  int sc = v;
#pragma unroll
  for (int off = 1; off < 64; off <<= 1) {
    int tv = __shfl_up(sc, off, 64);
    if (t >= off) sc += tv;
  }
  if (t < nb) bsum[t] = sc - v;
}

__global__ __launch_bounds__(256) void scan_out_kernel(const int* __restrict__ deg,
                                                       const int* __restrict__ bsum,
                                                       int* __restrict__ row_ptr,
                                                       int* __restrict__ cursor,
                                                       float* __restrict__ dis, int n) {
  int base = blockIdx.x * 1024 + threadIdx.x * 4;
  int loc[4];
  int s = 0;
#pragma unroll
  for (int u = 0; u < 4; ++u) {
    int i = base + u;
    loc[u] = (i < n) ? deg[i] : 0;
    s += (loc[u] + 7) & ~7;
  }
  int lane = threadIdx.x & 63, wave = threadIdx.x >> 6;
  int sc = s;
#pragma unroll
  for (int off = 1; off < 64; off <<= 1) {
    int tv = __shfl_up(sc, off, 64);
    if (lane >= off) sc += tv;
  }
  __shared__ int wtot[4];
  if (lane == 63) wtot[wave] = sc;
  __syncthreads();
  int pre = sc - s + bsum[blockIdx.x];
  for (int w = 0; w < wave; ++w) pre += wtot[w];
  if (blockIdx.x == 0 && threadIdx.x == 0) row_ptr[0] = 0;
  int running = pre;
#pragma unroll
  for (int u = 0; u < 4; ++u) {
    int i = base + u;
    if (i < n) {
      cursor[i] = running;
      dis[i] = (loc[u] > 0) ? (1.0f / sqrtf((float)loc[u])) : 0.0f;
      running += (loc[u] + 7) & ~7;
      row_ptr[i + 1] = running;
    }
  }
}

// XCD-cohort scatter: cohort c = blockIdx&7 owns rows [c*n/8,(c+1)*n/8).
__global__ __launch_bounds__(256) void scatter_x8(const int* __restrict__ row,
                                                  const int* __restrict__ col, int E,
                                                  int* __restrict__ cursor,
                                                  const float* __restrict__ dis,
                                                  const float* __restrict__ lamp,
                                                  unsigned int* __restrict__ cw, int n) {
  int c = blockIdx.x & 7;
  int j = blockIdx.x >> 3;
  int nj = gridDim.x >> 3;
  int lo = (c * n) >> 3;
  int hi = ((c + 1) * n) >> 3;
  float sc = -(2.0f / lamp[0]);
  for (int i = j * 256 + threadIdx.x; i < E; i += nj * 256) {
    int r = row[i];
    if (r < lo || r >= hi) continue;
    int cc = col[i];
    int pos = atomicAdd(&cursor[r], 1);
    float w = sc * dis[r] * dis[cc];
    cw[pos] = ((unsigned int)cc << 16) | (unsigned int)f2h_bits(w);
  }
}

// Pack W ([KREAL][64] f32, zero-padded to KT*32) into MFMA B-fragment order.
__device__ inline void wpk_pack(const float* __restrict__ W, ushort* __restrict__ Wpk,
                                int KREAL, int t) {
  int kt = t >> 8, nt = (t >> 6) & 3, l = t & 63;
  int col = nt * 16 + (l & 15);
  int kb = kt * 32 + ((l >> 4) << 3);
  ushort tmp[8];
#pragma unroll
  for (int j = 0; j < 8; ++j) {
    int k = kb + j;
    float v = (k < KREAL) ? W[(size_t)k * 64 + col] : 0.0f;
    tmp[j] = f2h_bits(v);
  }
  ushort4* dst = (ushort4*)Wpk + (size_t)((kt * 4 + nt) * 64 + l) * 2;
  dst[0] = make_ushort4(tmp[0], tmp[1], tmp[2], tmp[3]);
  dst[1] = make_ushort4(tmp[4], tmp[5], tmp[6], tmp[7]);
}

// One prep kernel: blocks [0,4) Wpk1, [4,18) Wpk2, [18,32) Wpk3, [32,..) x->T1.
__global__ __launch_bounds__(256) void prep_all_kernel(
    const float* __restrict__ W1, const float* __restrict__ W2,
    const float* __restrict__ W3, ushort* __restrict__ Wpk1, ushort* __restrict__ Wpk2,
    ushort* __restrict__ Wpk3, const float* __restrict__ x, ushort* __restrict__ T1,
    int n) {
  int b = blockIdx.x;
  if (b < 4) {
    wpk_pack(W1, Wpk1, 112, b * 256 + threadIdx.x);
  } else if (b < 18) {
    wpk_pack(W2, Wpk2, 448, (b - 4) * 256 + threadIdx.x);
  } else if (b < 32) {
    wpk_pack(W3, Wpk3, 448, (b - 18) * 256 + threadIdx.x);
  } else {
    int t = (b - 32) * 256 + threadIdx.x;
    if (t < n * 4) {
      int row = t >> 2, q = t & 3;
      float4 v = ((const float4*)x)[(size_t)row * 4 + q];
      ushort4 o;
      o.x = f2h_bits(v.x);
      o.y = f2h_bits(v.y);
      o.z = f2h_bits(v.z);
      o.w = f2h_bits(v.w);
      ((ushort4*)T1)[(size_t)row * 4 + q] = o;
    } else if (t < n * 8) {
      int t2 = t - n * 4;
      ((ushort4*)(T1 + (size_t)7 * n * 16))[t2] = make_ushort4(0, 0, 0, 0);
    }
  }
}

// ---------------------------------------------------------------------------
// SpMV on dense [N][SW] fp16 buffers, 16B (8 fp16) per lane, 8-edge batches,
// padded CSR (no predication).  SW=64: 8 lanes/row -> full 128B line per
// gather.  MODE 0: out = spmv(xin);  MODE 1: out = 2*spmv(xin) - sub.
// ---------------------------------------------------------------------------
template <int SW, int MODE>
__global__ __launch_bounds__(256) void spmv_dense(const int* __restrict__ row_ptr,
                                                  const unsigned int* __restrict__ cw,
                                                  const float* __restrict__ lamp,
                                                  const ushort* __restrict__ xin,
                                                  const ushort* __restrict__ sub,
                                                  ushort* __restrict__ xout, int n) {
  constexpr int LPR = SW / 8;     // lanes per row (16B each)
  constexpr int RPB = 256 / LPR;  // rows per block
  constexpr int B = 8;            // edge batch depth
  constexpr int EPL = B / LPR;    // cw entries per lane per batch (>=1)
  int i = blockIdx.x * RPB + threadIdx.y;
  if (i >= n) return;
  int f8 = threadIdx.x;  // 0..LPR-1
  int lane = (threadIdx.y * LPR + f8) & 63;
  int grpbase = lane - f8;
  float diag = 2.0f / lamp[0] - 1.0f;
  H8 xd;
  xd.q = *(const uint4*)(xin + (size_t)i * SW + f8 * 8);
  float a[8];
#pragma unroll
  for (int j = 0; j < 8; ++j) a[j] = diag * (float)xd.h[j];
  int s = row_ptr[i], e = row_ptr[i + 1];

  for (int j0 = s; j0 < e; j0 += B) {
    unsigned int pv[EPL];
#pragma unroll
    for (int u = 0; u < EPL; ++u) pv[u] = cw[j0 + f8 * EPL + u];
    H8 xv[B];
    float ww[B];
#pragma unroll
    for (int u = 0; u < B; ++u) {
      unsigned int pu = (unsigned int)__shfl((int)pv[u % EPL], grpbase + u / EPL, 64);
      ww[u] = h2f_bits(pu);
      xv[u].q = *(const uint4*)(xin + (size_t)(pu >> 16) * SW + f8 * 8);
    }
#pragma unroll
    for (int u = 0; u < B; ++u)
#pragma unroll
      for (int j = 0; j < 8; ++j) a[j] += ww[u] * (float)xv[u].h[j];
  }

  float r[8];
  if (MODE == 1) {
    H8 sv;
    sv.q = *(const uint4*)(sub + (size_t)i * SW + f8 * 8);
#pragma unroll
    for (int j = 0; j < 8; ++j) r[j] = 2.0f * a[j] - (float)sv.h[j];
  } else {
#pragma unroll
    for (int j = 0; j < 8; ++j) r[j] = a[j];
  }
  H8 o;
#pragma unroll
  for (int j = 0; j < 8; ++j) o.us[j] = f2h_bits(r[j]);
  *(uint4*)(xout + (size_t)i * SW + f8 * 8) = o.q;
}

// ---------------------------------------------------------------------------
// MFMA GEMM.  A: SW=64 -> slots [N][64], kt: slot=kt>>1, off=(kt&1)*32+(l>>4)*8.
//             SW=16 -> slots [N][16], kt spans slots {2kt,2kt+1}.
// Non-LAST: bias+relu -> dense fp16 [N][64] dst.
// LAST: fused FC head (in-register bias+relu+dot, 16-lane shfl_xor reduce).
// ---------------------------------------------------------------------------
template <int SW, int KT, bool LAST>
__global__ __launch_bounds__(256) void gemm_mfma(const ushort* __restrict__ A,
                                                 const ushort* __restrict__ Wpk,
                                                 const float* __restrict__ bias,
                                                 ushort* __restrict__ dsth,
                                                 const float* __restrict__ wfc,
                                                 const float* __restrict__ bfc,
                                                 float* __restrict__ dout, int n) {
  int l = threadIdx.x & 63;
  int tile = blockIdx.x * 4 + (threadIdx.x >> 6);
  int r0 = tile * 16;
  if (r0 >= n) return;
  size_t slotsz = (size_t)n * SW;
  int row = r0 + (l & 15);
  const f16x8* bp = (const f16x8*)Wpk + l;
  f32x4 c[4] = {{0.f, 0.f, 0.f, 0.f},
                {0.f, 0.f, 0.f, 0.f},
                {0.f, 0.f, 0.f, 0.f},
                {0.f, 0.f, 0.f, 0.f}};
#pragma unroll
  for (int kt = 0; kt < KT; ++kt) {
    int slot, off;
    if constexpr (SW == 64) {
      slot = kt >> 1;
      off = ((kt & 1) << 5) + ((l >> 4) << 3);
    } else {
      slot = 2 * kt + ((l >> 4) >> 1);
      off = ((l >> 4) & 1) << 3;
    }
    f16x8 af = *(const f16x8*)(A + slot * slotsz + (size_t)row * SW + off);
#pragma unroll
    for (int nt = 0; nt < 4; ++nt) {
      f16x8 bf = bp[(kt * 4 + nt) * 64];
      c[nt] = __builtin_amdgcn_mfma_f32_16x16x32_f16(af, bf, c[nt], 0, 0, 0);
    }
  }
  int rb = r0 + ((l >> 4) << 2);
  int cc = l & 15;
  if (LAST) {
    float bfc0 = bfc[0];
#pragma unroll
    for (int j = 0; j < 4; ++j) {
      float part = 0.0f;
#pragma unroll
      for (int nt = 0; nt < 4; ++nt) {
        int col = nt * 16 + cc;
        part += fmaxf(c[nt][j] + bias[col], 0.0f) * wfc[col];
      }
#pragma unroll
      for (int m = 1; m < 16; m <<= 1) part += __shfl_xor(part, m, 64);
      if (cc == 0) dout[rb + j] = part + bfc0;
    }
  } else {
#pragma unroll
    for (int nt = 0; nt < 4; ++nt) {
      int col = nt * 16 + cc;
      float bv = bias[col];
#pragma unroll
      for (int j = 0; j < 4; ++j) {
        float v = fmaxf(c[nt][j] + bv, 0.0f);
        dsth[(size_t)(rb + j) * 64 + col] = f2h_bits(v);
      }
    }
  }
}

extern "C" void kernel_launch(void* const* d_in, const int* in_sizes, int n_in, void* d_out,
                              int out_size, void* d_ws, size_t ws_size, hipStream_t stream) {
  const float* x = (const float*)d_in[0];
  const int* ei = (const int*)d_in[1];
  const float* lamp = (const float*)d_in[2];
  const float* W1 = (const float*)d_in[3];
  const float* b1 = (const float*)d_in[4];
  const float* W2 = (const float*)d_in[5];
  const float* b2 = (const float*)d_in[6];
  const float* W3 = (const float*)d_in[7];
  const float* b3 = (const float*)d_in[8];
  const float* Wfc = (const float*)d_in[9];
  const float* bfc = (const float*)d_in[10];

  const int N = in_sizes[0] / 16;  // 50000 (< 65536 required for packing)
  const int E = in_sizes[1] / 2;
  const int* row = ei;
  const int* col = ei + E;

  // ---- workspace carve ----
  char* p = (char*)d_ws;
  auto alloc = [&](size_t bytes) {
    char* r = p;
    p += WS_ALIGN(bytes);
    return r;
  };
  const size_t EPAD = (size_t)E + 8 * (size_t)N;  // padded CSR upper bound
  int* deg = (int*)alloc((size_t)N * 4);
  int* row_ptr = (int*)alloc((size_t)(N + 1) * 4);
  int* cursor = (int*)alloc((size_t)N * 4);
  unsigned int* cw = (unsigned int*)alloc(EPAD * 4);
  float* dis = (float*)alloc((size_t)N * 4);
  int* bsum = (int*)alloc(256 * 4);
  ushort* T1 = (ushort*)alloc((size_t)8 * N * 16 * 2);   // 8 slots [N][16] (slot7 = pad)
  ushort* TXC = (ushort*)alloc((size_t)7 * N * 64 * 2);  // 7 slots [N][64]
  ushort* Wpk1 = (ushort*)alloc((size_t)4 * 256 * 8 * 2);
  ushort* Wpk2 = (ushort*)alloc((size_t)14 * 256 * 8 * 2);
  ushort* Wpk3 = (ushort*)alloc((size_t)14 * 256 * 8 * 2);
  (void)ws_size;
  (void)n_in;
  (void)out_size;

  // ---- CSR build (padded rows; cw pre-zeroed so pads are col=0,w=+0) ----
  (void)hipMemsetAsync(deg, 0, (size_t)N * 4, stream);
  (void)hipMemsetAsync(cw, 0, EPAD * 4, stream);
  hist_kernel<<<(E + 255) / 256, 256, 0, stream>>>(row, E, deg);
  int nb = (N + 1023) / 1024;
  scan_sum_kernel<<<nb, 256, 0, stream>>>(deg, bsum, N);
  scan_bsum_kernel<<<1, 64, 0, stream>>>(bsum, nb);
  scan_out_kernel<<<nb, 256, 0, stream>>>(deg, bsum, row_ptr, cursor, dis, N);
  scatter_x8<<<2048, 256, 0, stream>>>(row, col, E, cursor, dis, lamp, cw, N);

  // ---- fused prep: W packing + x conversion ----
  prep_all_kernel<<<32 + (N * 8 + 255) / 256, 256, 0, stream>>>(W1, W2, W3, Wpk1, Wpk2, Wpk3,
                                                                x, T1, N);

  // ---- layer 1 (slots [N][16]; LPR=2, RPB=128) ----
  {
    int ssz = N * 16;  // ushorts per slot
    auto S = [&](int k) { return T1 + (size_t)k * ssz; };
    dim3 bs(2, 128);
    int gs = (N + 127) / 128;
    spmv_dense<16, 0><<<gs, bs, 0, stream>>>(row_ptr, cw, lamp, S(0), nullptr, S(1), N);
    for (int k = 2; k < 7; ++k)
      spmv_dense<16, 1><<<gs, bs, 0, stream>>>(row_ptr, cw, lamp, S(k - 1), S(k - 2), S(k),
                                               N);
    gemm_mfma<16, 4, false><<<(N / 16 + 3) / 4 + 1, 256, 0, stream>>>(T1, Wpk1, b1, TXC,
                                                                      nullptr, nullptr,
                                                                      nullptr, N);
  }

  // ---- layers 2,3 (dense [N][64] slots; LPR=8, RPB=32) ----
  for (int layer = 2; layer <= 3; ++layer) {
    int ssz = N * 64;  // ushorts per slot
    auto S = [&](int k) { return TXC + (size_t)k * ssz; };
    dim3 bs(8, 32);
    int gs = (N + 31) / 32;
    spmv_dense<64, 0><<<gs, bs, 0, stream>>>(row_ptr, cw, lamp, S(0), nullptr, S(1), N);
    for (int k = 2; k < 7; ++k)
      spmv_dense<64, 1><<<gs, bs, 0, stream>>>(row_ptr, cw, lamp, S(k - 1), S(k - 2), S(k),
                                               N);
    if (layer == 2)
      gemm_mfma<64, 14, false><<<(N / 16 + 3) / 4 + 1, 256, 0, stream>>>(TXC, Wpk2, b2, TXC,
                                                                         nullptr, nullptr,
                                                                         nullptr, N);
    else
      gemm_mfma<64, 14, true><<<(N / 16 + 3) / 4 + 1, 256, 0, stream>>>(TXC, Wpk3, b3,
                                                                        nullptr, Wfc, bfc,
                                                                        (float*)d_out, N);
  }
}